// Round 5
// baseline (252.178 us; speedup 1.0000x reference)
//
#include <hip/hip_runtime.h>

#define TSEQ 2048
#define NB 4
#define NH 16
#define HD 64
#define CEMB 1024
#define MROWS (NB*TSEQ)   // 8192

typedef _Float16 half8 __attribute__((ext_vector_type(8)));
typedef _Float16 half4_t __attribute__((ext_vector_type(4)));
typedef float floatx4 __attribute__((ext_vector_type(4)));

__device__ __forceinline__ floatx4 mfma16x32(half8 a, half8 b, floatx4 c) {
    return __builtin_amdgcn_mfma_f32_16x16x32_f16(a, b, c, 0, 0, 0);
}

__device__ __forceinline__ void async16(const _Float16* g, _Float16* l) {
    __builtin_amdgcn_global_load_lds((const __attribute__((address_space(1))) void*)g,
                                     (__attribute__((address_space(3))) void*)l, 16, 0, 0);
}

// ---------------- fp32 -> fp16 convert (8 elem/thread) ----------------
__global__ __launch_bounds__(256) void cvt_fp32_fp16(const float* __restrict__ in,
                                                     _Float16* __restrict__ out) {
    size_t i = ((size_t)blockIdx.x * 256 + threadIdx.x) * 8;
    float4 a = *(const float4*)(in + i);
    float4 b = *(const float4*)(in + i + 4);
    half8 h;
    h[0] = (_Float16)a.x; h[1] = (_Float16)a.y; h[2] = (_Float16)a.z; h[3] = (_Float16)a.w;
    h[4] = (_Float16)b.x; h[5] = (_Float16)b.y; h[6] = (_Float16)b.z; h[7] = (_Float16)b.w;
    *(half8*)(out + i) = h;
}

// ------------- transpose + convert: in fp32 [R][Ccols] -> out fp16 [Ccols][R] -------------
__global__ __launch_bounds__(256) void transpose_cvt(const float* __restrict__ in,
                                                     _Float16* __restrict__ out,
                                                     int R, int Ccols) {
    __shared__ float tile[32][33];
    int bx = blockIdx.x;
    int by = blockIdx.y;
    int tx = threadIdx.x, ty = threadIdx.y;
    int x = bx * 32 + tx;
#pragma unroll
    for (int i = 0; i < 32; i += 8) {
        int y = by * 32 + ty + i;
        tile[ty + i][tx] = in[(size_t)y * Ccols + x];
    }
    __syncthreads();
#pragma unroll
    for (int i = 0; i < 32; i += 8) {
        int oc = bx * 32 + ty + i;
        int orow = by * 32 + tx;
        out[(size_t)oc * R + orow] = (_Float16)tile[tx][ty + i];
    }
}

// ---------------- 256x256x64 8-wave GEMM, m201-template port (QKV GEMM) ----------------
// C[m][n] = sum_k A[m][k]*Bt[n][k], K=1024 (16 K-tiles of 64).  8 waves = 2M x 4N,
// per-wave 128x64 output (acc[8][4]).  LDS 128KB: A/B each as 2dbuf x 2 row-half
// buffers of 128x64 f16 (16KB).  Per K-tile: 4 phases x 16 MFMA (quadrants
// (mq,nq) = (0,0),(0,1),(1,0),(1,1)); per phase: {ds_read frags | stage one
// half-tile | s_barrier | setprio(1) 16 MFMA setprio(0) | lgkmcnt(0) | s_barrier}.
// Counted vmcnt(4) ONCE per K-tile (m201's T4): stages = p0:t+1.B0, p1:t+1.B1,
// p3:t+2.A0+A1; at the tile boundary the 4 newest loads (t+2's A halves) stay in
// flight.  WAR: all reads of a buffer drain (lgkm0+barrier) >=1 barrier before its
// overwriting stage issues.  Swizzle: 128B rows = 8 chunks of 16B; phys chunk =
// logical ^ (row&7); staged via inverse-permuted global source (linear LDS dest).
// ROUND-4 FIX: kk=1 sub-fragment (logical chunk 4+quad) reads phys chunk
// (quad^l7)^4 -> offset XOR 32, NOT +32 (the +32 crossed the row for l7>=4 and
// read garbage -> NaN).
__global__ __launch_bounds__(512, 2) void gemm256(const _Float16* __restrict__ A,
                                                  const _Float16* __restrict__ Bt,
                                                  _Float16* __restrict__ Ch,
                                                  _Float16* __restrict__ VTh,
                                                  int N, int K) {
    __shared__ __align__(16) _Float16 Ah[2][2][8192];   // [dbuf][mhalf][128*64]
    __shared__ __align__(16) _Float16 Bh[2][2][8192];   // [dbuf][nhalf][128*64]

    const int tid = threadIdx.x;
    const int wv = tid >> 6, lane = tid & 63;
    const int wm = wv >> 2, wn = wv & 3;
    const int wnh = wn >> 1, wnl = wn & 1;
    const int l16 = lane & 15, quad = lane >> 4;
    const int l7 = l16 & 7;

    // L2 group swizzle (GROUP_M = 8 bm-rows per group); gridDim.x = 32 divisible by 8.
    const int pid = blockIdx.x + gridDim.x * blockIdx.y;
    const int nn = gridDim.y;
    const int pig = 8 * nn;
    const int gid = pid / pig;
    const int rem = pid - gid * pig;
    const int bm = gid * 8 + (rem & 7);
    const int bn = rem >> 3;

    // Staging source: thread -> chunk c = tid: row = c>>3, phys chunk c&7 holds
    // logical chunk (c&7)^(row&7)  (inverse of the read swizzle; XOR involution).
    const int rS = tid >> 3;
    const int kS = ((tid & 7) ^ (rS & 7)) * 8;
    const _Float16* Asrc = A  + (size_t)(bm * 256 + rS) * K + kS;
    const _Float16* Bsrc = Bt + (size_t)(bn * 256 + rS) * K + kS;

    auto stA = [&](int d, int mh, int tt) {
        const _Float16* s = Asrc + (size_t)(mh * 128) * K + tt * 64;
        async16(s, &Ah[d][mh][wv * 512]);
        async16(s + (size_t)64 * K, &Ah[d][mh][4096 + wv * 512]);
    };
    auto stB = [&](int d, int nh, int tt) {
        const _Float16* s = Bsrc + (size_t)(nh * 128) * K + tt * 64;
        async16(s, &Bh[d][nh][wv * 512]);
        async16(s + (size_t)64 * K, &Bh[d][nh][4096 + wv * 512]);
    };

    const floatx4 zero = {0.f, 0.f, 0.f, 0.f};
    floatx4 acc[8][4];
#pragma unroll
    for (int i = 0; i < 8; i++)
#pragma unroll
        for (int j = 0; j < 4; j++) acc[i][j] = zero;

    // Read swizzle: kk=0 logical chunk = quad -> phys = quad^l7 (sw0);
    // kk=1 logical chunk = 4+quad -> phys = (quad^l7)^4 -> offset ^32.
    const int sw0 = (quad ^ l7) * 8;
    const int aoff = l16 * 64 + sw0;                  // + mq*4096 + i*1024 (^32 for kk=1)
    const int boff = (wnl * 64 + l16) * 64 + sw0;     // + nq*2048 + j*1024 (^32)

    half8 af[4][2];        // A-frags for current mq (re-read at phase 2)
    half8 bf[2][2][2];     // B-frags for both nq, live whole tile

#define RD_A(mq)                                                              \
    _Pragma("unroll") for (int i_ = 0; i_ < 4; i_++) {                        \
        af[i_][0] = *(const half8*)&Ac[(mq)*4096 + (aoff + i_*1024)];         \
        af[i_][1] = *(const half8*)&Ac[(mq)*4096 + ((aoff + i_*1024) ^ 32)];  \
    }
#define RD_B(nq)                                                              \
    _Pragma("unroll") for (int j_ = 0; j_ < 2; j_++) {                        \
        bf[nq][j_][0] = *(const half8*)&Bc[(nq)*2048 + (boff + j_*1024)];     \
        bf[nq][j_][1] = *(const half8*)&Bc[(nq)*2048 + ((boff + j_*1024) ^ 32)]; \
    }
#define MFMA_Q(mq, nq)                                                        \
    do {                                                                      \
        __builtin_amdgcn_s_setprio(1);                                        \
        _Pragma("unroll") for (int i_ = 0; i_ < 4; i_++)                      \
            _Pragma("unroll") for (int j_ = 0; j_ < 2; j_++) {                \
                acc[(mq)*4+i_][(nq)*2+j_] =                                   \
                    mfma16x32(af[i_][0], bf[nq][j_][0], acc[(mq)*4+i_][(nq)*2+j_]); \
                acc[(mq)*4+i_][(nq)*2+j_] =                                   \
                    mfma16x32(af[i_][1], bf[nq][j_][1], acc[(mq)*4+i_][(nq)*2+j_]); \
            }                                                                 \
        __builtin_amdgcn_s_setprio(0);                                        \
    } while (0)
#define ENDP()                                                                \
    asm volatile("s_waitcnt lgkmcnt(0)\n\ts_barrier" ::: "memory");           \
    __builtin_amdgcn_sched_barrier(0)

    // Prologue: tile0 all 4 halves + tile1 A0,A1 (12 loads); vmcnt(4) -> tile0 landed.
    stA(0, 0, 0); stA(0, 1, 0); stB(0, 0, 0); stB(0, 1, 0);
    stA(1, 0, 1); stA(1, 1, 1);
    asm volatile("s_waitcnt vmcnt(4)\n\ts_barrier" ::: "memory");

    for (int t = 0; t < 16; ++t) {
        const int d = t & 1;
        const _Float16* Ac = &Ah[d][wm][0];
        const _Float16* Bc = &Bh[d][wnh][0];

        // phase 0: quadrant (0,0); stage t+1:B0
        RD_A(0); RD_B(0);
        if (t + 1 < 16) stB(d ^ 1, 0, t + 1);
        asm volatile("s_barrier" ::: "memory");
        MFMA_Q(0, 0);
        ENDP();

        // phase 1: quadrant (0,1); stage t+1:B1
        RD_B(1);
        if (t + 1 < 16) stB(d ^ 1, 1, t + 1);
        asm volatile("s_barrier" ::: "memory");
        MFMA_Q(0, 1);
        ENDP();

        // phase 2: quadrant (1,0); A-frags re-read (same regs), no stage
        RD_A(1);
        asm volatile("s_barrier" ::: "memory");
        MFMA_Q(1, 0);
        ENDP();

        // phase 3: quadrant (1,1); stage t+2:A0,A1 (A-half reads drained at phase 2)
        if (t + 2 < 16) { stA(d, 0, t + 2); stA(d, 1, t + 2); }
        asm volatile("s_barrier" ::: "memory");
        MFMA_Q(1, 1);
        // Tile-boundary counted wait: t+1's 4 halves landed, t+2's A halves in flight.
        if (t < 14) {
            asm volatile("s_waitcnt vmcnt(4) lgkmcnt(0)\n\ts_barrier" ::: "memory");
        } else if (t == 14) {
            asm volatile("s_waitcnt vmcnt(0) lgkmcnt(0)\n\ts_barrier" ::: "memory");
        }
        __builtin_amdgcn_sched_barrier(0);
    }
#undef RD_A
#undef RD_B
#undef MFMA_Q
#undef ENDP

    // Epilogue: QKV split-scatter (which = bn>>2: 0=Q, 1=K, 2=V; N=3072, BN=256)
    const int which = bn >> 2;
    if (which < 2) {
#pragma unroll
        for (int j = 0; j < 4; j++) {
            int n = bn * 256 + wn * 64 + j * 16 + l16;
            int c = n & 1023, h = c >> 6, dd = c & 63;
            _Float16* dst = Ch + (size_t)which * ((size_t)MROWS * CEMB)
                               + (size_t)h * (TSEQ * HD) + dd;
#pragma unroll
            for (int i = 0; i < 8; i++) {
                int row = bm * 256 + wm * 128 + i * 16 + quad * 4;
#pragma unroll
                for (int r = 0; r < 4; r++) {
                    int m = row + r;
                    int b = m >> 11, tt = m & 2047;
                    dst[(size_t)b * (NH * TSEQ * HD) + (size_t)tt * HD] = (_Float16)acc[i][j][r];
                }
            }
        }
    } else {
        // V^T: [bh][d][t], 4 consecutive t -> packed b64 store
#pragma unroll
        for (int j = 0; j < 4; j++) {
            int n = bn * 256 + wn * 64 + j * 16 + l16;
            int c = n & 1023, h = c >> 6, dd = c & 63;
#pragma unroll
            for (int i = 0; i < 8; i++) {
                int m0 = bm * 256 + wm * 128 + i * 16 + quad * 4;
                int b = m0 >> 11, tt = m0 & 2047;
                half4_t pk;
#pragma unroll
                for (int r = 0; r < 4; r++) pk[r] = (_Float16)acc[i][j][r];
                *(half4_t*)&VTh[(((size_t)(b * NH + h)) * HD + dd) * TSEQ + tt] = pk;
            }
        }
    }
}

// ---------------- NT GEMM (proj), 4-wave / 128x64-per-wave / 2 blocks-per-CU ----------
template<int MODE>
__global__ __launch_bounds__(256, 2) void gemm_w4(const _Float16* __restrict__ A,
                                                  const _Float16* __restrict__ Bt,
                                                  float* __restrict__ Cf,
                                                  _Float16* __restrict__ Ch,
                                                  _Float16* __restrict__ VTh,
                                                  int N, int K) {
    __shared__ __align__(16) _Float16 As[3][128 * 32];   // 24KB
    __shared__ __align__(16) _Float16 Bs[3][256 * 32];   // 48KB

    const int tid = threadIdx.x;
    const int wv = tid >> 6, lane = tid & 63;
    const int l16 = lane & 15, quad = lane >> 4;

    const int pid = blockIdx.x + gridDim.x * blockIdx.y;
    const int nn = gridDim.y;
    const int pig = 8 * nn;
    const int gid = pid / pig;
    const int rem = pid - gid * pig;
    const int bm = gid * 8 + (rem & 7);
    const int bn = rem >> 3;

    const int rA = tid >> 2;
    const int kA = ((tid & 3) ^ ((tid >> 3) & 3)) * 8;
    const _Float16* Ag = A  + (size_t)(bm * 128 + rA) * K + kA;
    const _Float16* Bg = Bt + (size_t)(bn * 256 + rA) * K + kA;

    auto stage = [&](int slot, int ss) {
        const int k0 = ss * 32;
#pragma unroll
        for (int u = 0; u < 2; u++)
            async16(Ag + (size_t)(u * 64) * K + k0, &As[slot][tid * 8 + u * 2048]);
#pragma unroll
        for (int u = 0; u < 4; u++)
            async16(Bg + (size_t)(u * 64) * K + k0, &Bs[slot][tid * 8 + u * 2048]);
    };

    const floatx4 zero = {0.f, 0.f, 0.f, 0.f};
    floatx4 acc[8][4];
#pragma unroll
    for (int i = 0; i < 8; i++)
#pragma unroll
        for (int j = 0; j < 4; j++) acc[i][j] = zero;

    const int sw2 = (quad ^ ((l16 >> 1) & 3)) * 8;
    const int offA = l16 * 32 + sw2;
    const int offB = (wv * 64 + l16) * 32 + sw2;

#define PHASE(s, slot, slot2, STG, WAIT)                                        \
    do {                                                                        \
        if (STG) stage(slot2, (s) + 2);                                         \
        half8 af[8], bf[4];                                                     \
        _Pragma("unroll") for (int i_ = 0; i_ < 8; i_++)                        \
            af[i_] = *(const half8*)&As[slot][offA + i_ * 512];                 \
        _Pragma("unroll") for (int j_ = 0; j_ < 4; j_++)                        \
            bf[j_] = *(const half8*)&Bs[slot][offB + j_ * 512];                 \
        __builtin_amdgcn_s_setprio(1);                                          \
        _Pragma("unroll") for (int i_ = 0; i_ < 8; i_++)                        \
            _Pragma("unroll") for (int j_ = 0; j_ < 4; j_++)                    \
                acc[i_][j_] = mfma16x32(af[i_], bf[j_], acc[i_][j_]);           \
        __builtin_amdgcn_s_setprio(0);                                          \
        if (WAIT == 2)                                                          \
            asm volatile("s_waitcnt vmcnt(6) lgkmcnt(0)\n\ts_barrier" ::: "memory"); \
        else if (WAIT == 1)                                                     \
            asm volatile("s_waitcnt vmcnt(0) lgkmcnt(0)\n\ts_barrier" ::: "memory"); \
        __builtin_amdgcn_sched_barrier(0);                                      \
    } while (0)

    stage(0, 0); stage(1, 1); stage(2, 2);
    asm volatile("s_waitcnt vmcnt(12)\n\ts_barrier" ::: "memory");

    for (int it = 0; it < 10; ++it) {
        const int s0 = it * 3;
        PHASE(s0 + 0, 0, 2, 1, 2);
        PHASE(s0 + 1, 1, 0, 1, 2);
        PHASE(s0 + 2, 2, 1, 1, 2);
    }
    PHASE(30, 0, 0, 0, 1);
    PHASE(31, 1, 0, 0, 0);
#undef PHASE

    if (MODE == 1) {
#pragma unroll
        for (int i = 0; i < 8; i++) {
            int row = bm * 128 + i * 16 + quad * 4;
#pragma unroll
            for (int j = 0; j < 4; j++) {
                int col = bn * 256 + wv * 64 + j * 16 + l16;
#pragma unroll
                for (int r = 0; r < 4; r++)
                    Cf[(size_t)(row + r) * N + col] = acc[i][j][r];
            }
        }
    }
}

// ---------------- flash attention: 256 q / block, 512 threads, 8 waves ----------------
__global__ __launch_bounds__(512, 4) void attn_fwd(const _Float16* __restrict__ Qg,
                                                   const _Float16* __restrict__ Kg,
                                                   const _Float16* __restrict__ VTg,
                                                   _Float16* __restrict__ Y) {
    __shared__ __align__(16) _Float16 Ks[2][4096];   // [64 keys][64 d], swizzled
    __shared__ __align__(16) _Float16 Vt[2][4096];   // [64 d][64 keys], swizzled

    const int tid = threadIdx.x;
    const int w = tid >> 6, lane = tid & 63;
    const int l16 = lane & 15, quad = lane >> 4;
    const int bh = blockIdx.y;
    const int x = blockIdx.x;    // 0..7
    const int b = bh >> 4, h = bh & 15;
    const int qt = (b < 2) ? x : (7 - x);

    const _Float16* Qb = Qg + (size_t)bh * TSEQ * HD;
    const _Float16* Kb = Kg + (size_t)bh * TSEQ * HD;
    const _Float16* Vb = VTg + (size_t)bh * HD * TSEQ;

    const _Float16 ksc = (_Float16)(0.125f * 1.44269504089f);  // 1/sqrt(64)*log2(e)
    const floatx4 zero = {0.f, 0.f, 0.f, 0.f};

    half8 qf[2][2];
#pragma unroll
    for (int g = 0; g < 2; g++) {
        const _Float16* qrow = Qb + (size_t)(qt * 256 + g * 128 + w * 16 + l16) * HD;
        qf[g][0] = *(const half8*)(qrow + quad * 8);
        qf[g][1] = *(const half8*)(qrow + 32 + quad * 8);
#pragma unroll
        for (int e = 0; e < 8; e++) { qf[g][0][e] *= ksc; qf[g][1][e] *= ksc; }
    }

    floatx4 o[2][4];
#pragma unroll
    for (int g = 0; g < 2; g++)
#pragma unroll
        for (int dt = 0; dt < 4; dt++) o[g][dt] = zero;
    float lsum[2] = {0.f, 0.f};

    const int srow8 = lane >> 3;
    const int scol8 = ((lane & 7) ^ (lane >> 3)) * 8;   // XOR-8 swizzled col (halves)

    auto stage = [&](int bf, int kt2) {
        const int row = w * 8 + srow8;                  // 8 waves -> 1 chunk each
        async16(Kb + (size_t)(kt2 * 64 + row) * HD + scol8, &Ks[bf][w * 512]);
        async16(Vb + (size_t)row * TSEQ + kt2 * 64 + scol8, &Vt[bf][w * 512]);
    };

    const int kmax = 4 * qt + 3;
    stage(0, 0);
    int buf = 0;
    for (int kt = 0; kt <= kmax; ++kt) {
        __syncthreads();                   // buf staged (vmcnt drain), buf^1 free
        if (kt < kmax) stage(buf ^ 1, kt + 1);

        // K fragments (shared by both q-groups)
        half8 kf0[4], kf1[4];
#pragma unroll
        for (int nj = 0; nj < 4; nj++) {
            const int rb = (nj * 16 + l16) * 64;
            kf0[nj] = *(const half8*)&Ks[buf][rb + ((quad ^ (l16 & 7)) * 8)];
            kf1[nj] = *(const half8*)&Ks[buf][rb + (((quad ^ 4) ^ (l16 & 7)) * 8)];
        }

        const bool doA = (kt <= 4 * qt + 1);   // g=0 needs tiles up to 4qt+1
        half8 pf[2][2];
#pragma unroll
        for (int g = 0; g < 2; g++) {
            if (g == 0 && !doA) continue;  // wave-uniform skip (last 2 tiles g=1 only)
            floatx4 st[4];
#pragma unroll
            for (int nj = 0; nj < 4; nj++) {
                floatx4 t = mfma16x32(kf0[nj], qf[g][0], zero);
                st[nj] = mfma16x32(kf1[nj], qf[g][1], t);
            }
            if (kt * 64 + 63 > qt * 256 + g * 128 + w * 16) {   // boundary tiles only
                const int klim = qt * 256 + g * 128 + w * 16 + l16 - kt * 64;
#pragma unroll
                for (int nj = 0; nj < 4; nj++)
#pragma unroll
                    for (int r = 0; r < 4; r++) {
                        int key = nj * 16 + quad * 4 + r;
                        if (key > klim) st[nj][r] = -1e30f;   // exp2 -> 0
                    }
            }
#pragma unroll
            for (int nj = 0; nj < 4; nj++)
#pragma unroll
                for (int r = 0; r < 4; r++) {
                    float p = __builtin_amdgcn_exp2f(st[nj][r]);
                    lsum[g] += p;
                    pf[g][nj >> 1][(nj & 1) * 4 + r] = (_Float16)p;
                }
        }

        // O += P*V, paired 16x16x32; V-fragments shared across groups
#pragma unroll
        for (int u = 0; u < 2; u++) {
#pragma unroll
            for (int dt = 0; dt < 4; dt++) {
                const int rb = (dt * 16 + l16) * 64;
                const int g0 = u * 4 + (quad >> 1);
                const int sub = (quad & 1) * 4;
                half4_t lo = *(const half4_t*)&Vt[buf][rb + ((g0 ^ (l16 & 7)) * 8 + sub)];
                half4_t hi = *(const half4_t*)&Vt[buf][rb + (((g0 + 2) ^ (l16 & 7)) * 8 + sub)];
                half8 vf;
                vf[0] = lo[0]; vf[1] = lo[1]; vf[2] = lo[2]; vf[3] = lo[3];
                vf[4] = hi[0]; vf[5] = hi[1]; vf[6] = hi[2]; vf[7] = hi[3];
                if (doA) o[0][dt] = mfma16x32(pf[0][u], vf, o[0][dt]);
                o[1][dt] = mfma16x32(pf[1][u], vf, o[1][dt]);
            }
        }
        buf ^= 1;
    }

#pragma unroll
    for (int g = 0; g < 2; g++) {
        float lt = lsum[g];
        lt += __shfl_xor(lt, 16);
        lt += __shfl_xor(lt, 32);      // lt = full l for query w*16+l16 (this group)
        float linv[4];
#pragma unroll
        for (int r = 0; r < 4; r++) linv[r] = 1.0f / __shfl(lt, quad * 4 + r);
#pragma unroll
        for (int dt = 0; dt < 4; dt++)
#pragma unroll
            for (int r = 0; r < 4; r++) {
                int q = qt * 256 + g * 128 + w * 16 + quad * 4 + r;
                int d = dt * 16 + l16;
                Y[((size_t)(b * TSEQ + q)) * CEMB + h * HD + d] = (_Float16)(o[g][dt][r] * linv[r]);
            }
    }
}

extern "C" void kernel_launch(void* const* d_in, const int* in_sizes, int n_in,
                              void* d_out, int out_size, void* d_ws, size_t ws_size,
                              hipStream_t stream) {
    const float* x0     = (const float*)d_in[0];
    const float* w_attn = (const float*)d_in[1];
    const float* w_proj = (const float*)d_in[2];
    float* out = (float*)d_out;

    _Float16* xh  = (_Float16*)d_ws;                       // [8192][1024]
    _Float16* wqt = xh  + (size_t)MROWS * CEMB;            // [3072][1024] (w_attn^T)
    _Float16* wpt = wqt + (size_t)3 * CEMB * CEMB;         // [1024][1024] (w_proj^T)
    _Float16* qh  = wpt + (size_t)CEMB * CEMB;             // Q [bh][t][d]
    _Float16* kh  = qh  + (size_t)MROWS * CEMB;            // K [bh][t][d]
    _Float16* vt  = kh  + (size_t)MROWS * CEMB;            // V^T [bh][d][t]
    _Float16* yh  = vt  + (size_t)MROWS * CEMB;            // [8192][1024]

    cvt_fp32_fp16<<<(MROWS * CEMB) / (256 * 8), 256, 0, stream>>>(x0, xh);
    transpose_cvt<<<dim3(3 * CEMB / 32, CEMB / 32), dim3(32, 8), 0, stream>>>(w_attn, wqt, CEMB, 3 * CEMB);
    transpose_cvt<<<dim3(CEMB / 32, CEMB / 32), dim3(32, 8), 0, stream>>>(w_proj, wpt, CEMB, CEMB);

    gemm256<<<dim3(MROWS / 256, 3 * CEMB / 256), 512, 0, stream>>>(xh, wqt, qh, vt, 3 * CEMB, CEMB);
    attn_fwd<<<dim3(TSEQ / 256, NB * NH), 512, 0, stream>>>(qh, kh, vt, yh);
    gemm_w4<1><<<dim3(MROWS / 128, CEMB / 256), 256, 0, stream>>>(yh, wpt, out, nullptr, nullptr, CEMB, CEMB);
}

// Round 6
// 234.459 us; speedup vs baseline: 1.0756x; 1.0756x over previous
//
#include <hip/hip_runtime.h>

#define TSEQ 2048
#define NB 4
#define NH 16
#define HD 64
#define CEMB 1024
#define MROWS (NB*TSEQ)   // 8192

typedef _Float16 half8 __attribute__((ext_vector_type(8)));
typedef _Float16 half4_t __attribute__((ext_vector_type(4)));
typedef float floatx4 __attribute__((ext_vector_type(4)));

__device__ __forceinline__ floatx4 mfma16x32(half8 a, half8 b, floatx4 c) {
    return __builtin_amdgcn_mfma_f32_16x16x32_f16(a, b, c, 0, 0, 0);
}

__device__ __forceinline__ void async16(const _Float16* g, _Float16* l) {
    __builtin_amdgcn_global_load_lds((const __attribute__((address_space(1))) void*)g,
                                     (__attribute__((address_space(3))) void*)l, 16, 0, 0);
}

// ---------------- fp32 -> fp16 convert (8 elem/thread) ----------------
__global__ __launch_bounds__(256) void cvt_fp32_fp16(const float* __restrict__ in,
                                                     _Float16* __restrict__ out) {
    size_t i = ((size_t)blockIdx.x * 256 + threadIdx.x) * 8;
    float4 a = *(const float4*)(in + i);
    float4 b = *(const float4*)(in + i + 4);
    half8 h;
    h[0] = (_Float16)a.x; h[1] = (_Float16)a.y; h[2] = (_Float16)a.z; h[3] = (_Float16)a.w;
    h[4] = (_Float16)b.x; h[5] = (_Float16)b.y; h[6] = (_Float16)b.z; h[7] = (_Float16)b.w;
    *(half8*)(out + i) = h;
}

// ------------- transpose + convert: in fp32 [R][Ccols] -> out fp16 [Ccols][R] -------------
__global__ __launch_bounds__(256) void transpose_cvt(const float* __restrict__ in,
                                                     _Float16* __restrict__ out,
                                                     int R, int Ccols) {
    __shared__ float tile[32][33];
    int bx = blockIdx.x;
    int by = blockIdx.y;
    int tx = threadIdx.x, ty = threadIdx.y;
    int x = bx * 32 + tx;
#pragma unroll
    for (int i = 0; i < 32; i += 8) {
        int y = by * 32 + ty + i;
        tile[ty + i][tx] = in[(size_t)y * Ccols + x];
    }
    __syncthreads();
#pragma unroll
    for (int i = 0; i < 32; i += 8) {
        int oc = bx * 32 + ty + i;
        int orow = by * 32 + tx;
        out[(size_t)oc * R + orow] = (_Float16)tile[tx][ty + i];
    }
}

// ---------------- NT GEMM, counted-vmcnt ring + reg-dbuf + PINNED issue order --------
// Rounds 0-5 post-mortem: every schedule measured the SERIAL SUM of the LDS burst and
// the MFMA burst (~5800cy/tile = 2480 MFMA + 2260 ds_read + 750 stage + barriers).
// Round 2's reg-dbuf failed to overlap them because nothing pinned the ds_reads BEFORE
// the MFMA cluster -- the compiler may sink reads toward their (next-phase) use, and
// the asm "memory" clobber only orders them vs the barrier, not vs register-only MFMAs.
// Fix: phase s = { LDF(slice s+1, alt regs) ; stage(slice s+4) ; sched_barrier(0) ;
//                  MM(slice s) ; vmcnt(6)+lgkm(0)+barrier ; sched_barrier(0) }
// The sched_barrier(0) guarantees all 8 ds_read_b128 + 3 global_load_lds issue before
// the 16-MFMA cluster, so the LDS pipe (~1030cy/phase incl. staging writes) runs under
// the matrix pipe (~620cy/phase).  Compiler auto-inserts lgkmcnt(8) before MM's
// operand use.  vmcnt(6): slice s+1 (staged at phase s-3) landed by end of phase s-1;
// lgkm(0) at phase end closes the slot-WAR vs phase s+1's stage.
template<int MODE>
__global__ __launch_bounds__(512, 2) void gemm_nt8(const _Float16* __restrict__ A,
                                                   const _Float16* __restrict__ Bt,
                                                   float* __restrict__ Cf,
                                                   _Float16* __restrict__ Ch,
                                                   _Float16* __restrict__ VTh,
                                                   int N, int K) {
    // K is 1024 for both call sites; pipeline tail is specialized for NS=32.
    __shared__ __align__(16) _Float16 As[4][128 * 32];
    __shared__ __align__(16) _Float16 Bs[4][256 * 32];

    const int tid = threadIdx.x;
    const int wv = tid >> 6, lane = tid & 63;
    const int wm = wv >> 2, wn = wv & 3;
    const int l16 = lane & 15, quad = lane >> 4;

    // L2 group swizzle (GROUP_M = 8 bm-rows per group)
    const int pid = blockIdx.x + gridDim.x * blockIdx.y;
    const int nn = gridDim.y;
    const int pig = 8 * nn;
    const int gid = pid / pig;
    const int rem = pid - gid * pig;
    const int bm = gid * 8 + (rem & 7);
    const int bn = rem >> 3;

    // Staging: chunk c = tid (512 chunks of 16B per 128x32 half); row = c>>2,
    // source col chunk = (c&3) ^ ((row>>1)&3)  (inverse of the read swizzle).
    const int rA = tid >> 2;
    const int kA = ((tid & 3) ^ ((rA >> 1) & 3)) * 8;
    const _Float16* Ag  = A  + (size_t)(bm * 128 + rA) * K + kA;
    const _Float16* Bg0 = Bt + (size_t)(bn * 256 + rA) * K + kA;
    const _Float16* Bg1 = Bg0 + (size_t)128 * K;

    auto stage = [&](int slot, int ss) {
        async16(Ag  + ss * 32, &As[slot][wv * 512]);
        async16(Bg0 + ss * 32, &Bs[slot][wv * 512]);
        async16(Bg1 + ss * 32, &Bs[slot][4096 + wv * 512]);
    };

    const floatx4 zero = {0.f, 0.f, 0.f, 0.f};
    floatx4 acc[4][4];
#pragma unroll
    for (int i = 0; i < 4; i++)
#pragma unroll
        for (int j = 0; j < 4; j++) acc[i][j] = zero;

    const int sw2 = (quad ^ ((l16 >> 1) & 3)) * 8;    // read-side swizzle (0-conflict)
    const int offA = (wm * 64 + l16) * 32 + sw2;
    const int offB = (wn * 64 + l16) * 32 + sw2;

    half8 fa[2][4], fb[2][4];   // double-buffered fragments; index always compile-time

#define LDF(d, slot)                                                         \
    do {                                                                     \
        _Pragma("unroll") for (int i_ = 0; i_ < 4; i_++)                     \
            fa[d][i_] = *(const half8*)&As[slot][offA + i_ * 512];           \
        _Pragma("unroll") for (int j_ = 0; j_ < 4; j_++)                     \
            fb[d][j_] = *(const half8*)&Bs[slot][offB + j_ * 512];           \
    } while (0)

#define MM(d)                                                                \
    do {                                                                     \
        __builtin_amdgcn_s_setprio(1);                                       \
        _Pragma("unroll") for (int i_ = 0; i_ < 4; i_++)                     \
            _Pragma("unroll") for (int j_ = 0; j_ < 4; j_++)                 \
                acc[i_][j_] = mfma16x32(fa[d][i_], fb[d][j_], acc[i_][j_]);  \
        __builtin_amdgcn_s_setprio(0);                                       \
    } while (0)

    // Prologue: slices 0..3 in flight (12 loads); vmcnt(6) -> slices 0,1 landed.
    stage(0, 0); stage(1, 1); stage(2, 2); stage(3, 3);
    asm volatile("s_waitcnt vmcnt(6)\n\ts_barrier" ::: "memory");
    LDF(0, 0);                                   // frags slice 0 resident
    // Drain prologue reads before phase 0's stage can overwrite slot 0 (WAR hygiene;
    // one-time ~120cy).
    asm volatile("s_waitcnt lgkmcnt(0)" ::: "memory");

    for (int it = 0; it < 7; ++it) {             // steady phases s = 0..27
#pragma unroll
        for (int p = 0; p < 4; ++p) {            // s = it*4+p; slot(s+4) = p
            LDF((p & 1) ^ 1, (p + 1) & 3);       // frags slice s+1 (landed: prev vmcnt)
            stage(p, it * 4 + p + 4);            // slice s+4 -> slot p
            __builtin_amdgcn_sched_barrier(0);   // PIN: reads+stage issue before MFMAs
            MM(p & 1);                           // slice s overlaps the LDS burst
            asm volatile("s_waitcnt vmcnt(6) lgkmcnt(0)\n\ts_barrier" ::: "memory");
            __builtin_amdgcn_sched_barrier(0);
        }
    }
    // Tail: slices 28..31, no more staging.  Barriers kept (landing guarantee is
    // collective: each wave reads rows staged by other waves).
    LDF(1, 1);
    __builtin_amdgcn_sched_barrier(0);
    MM(0);                                       // read slice 29, mfma slice 28
    asm volatile("s_waitcnt vmcnt(3)\n\ts_barrier" ::: "memory");   // slice 30 landed
    __builtin_amdgcn_sched_barrier(0);
    LDF(0, 2);
    __builtin_amdgcn_sched_barrier(0);
    MM(1);                                       // read slice 30, mfma slice 29
    asm volatile("s_waitcnt vmcnt(0)\n\ts_barrier" ::: "memory");   // slice 31 landed
    __builtin_amdgcn_sched_barrier(0);
    LDF(1, 3);
    __builtin_amdgcn_sched_barrier(0);
    MM(0);                                       // read slice 31, mfma slice 30
    MM(1);                                       // mfma slice 31
#undef LDF
#undef MM

    if (MODE == 1) {
#pragma unroll
        for (int i = 0; i < 4; i++) {
            int row = bm * 128 + wm * 64 + i * 16 + quad * 4;
#pragma unroll
            for (int j = 0; j < 4; j++) {
                int col = bn * 256 + wn * 64 + j * 16 + l16;
#pragma unroll
                for (int r = 0; r < 4; r++)
                    Cf[(size_t)(row + r) * N + col] = acc[i][j][r];
            }
        }
    } else {
        const int which = bn >> 2;   // block-uniform: 0=Q, 1=K, 2=V (BN=256)
        if (which < 2) {
#pragma unroll
            for (int j = 0; j < 4; j++) {
                int n = bn * 256 + wn * 64 + j * 16 + l16;
                int c = n & 1023, h = c >> 6, d = c & 63;
                _Float16* dst = Ch + (size_t)which * ((size_t)MROWS * CEMB)
                                   + (size_t)h * (TSEQ * HD) + d;
#pragma unroll
                for (int i = 0; i < 4; i++) {
                    int row = bm * 128 + wm * 64 + i * 16 + quad * 4;
#pragma unroll
                    for (int r = 0; r < 4; r++) {
                        int m = row + r;
                        int b = m >> 11, t = m & 2047;
                        dst[(size_t)b * (NH * TSEQ * HD) + (size_t)t * HD] = (_Float16)acc[i][j][r];
                    }
                }
            }
        } else {
            // V^T: [bh][d][t], 4 consecutive t -> packed b64 store
#pragma unroll
            for (int j = 0; j < 4; j++) {
                int n = bn * 256 + wn * 64 + j * 16 + l16;
                int c = n & 1023, h = c >> 6, d = c & 63;
#pragma unroll
                for (int i = 0; i < 4; i++) {
                    int m0 = bm * 128 + wm * 64 + i * 16 + quad * 4;
                    int b = m0 >> 11, t = m0 & 2047;
                    half4_t pk;
#pragma unroll
                    for (int r = 0; r < 4; r++) pk[r] = (_Float16)acc[i][j][r];
                    *(half4_t*)&VTh[(((size_t)(b * NH + h)) * HD + d) * TSEQ + t] = pk;
                }
            }
        }
    }
}

// ---------------- flash attention: 256 q / block, 512 threads, 8 waves ----------------
__global__ __launch_bounds__(512, 4) void attn_fwd(const _Float16* __restrict__ Qg,
                                                   const _Float16* __restrict__ Kg,
                                                   const _Float16* __restrict__ VTg,
                                                   _Float16* __restrict__ Y) {
    __shared__ __align__(16) _Float16 Ks[2][4096];   // [64 keys][64 d], swizzled
    __shared__ __align__(16) _Float16 Vt[2][4096];   // [64 d][64 keys], swizzled

    const int tid = threadIdx.x;
    const int w = tid >> 6, lane = tid & 63;
    const int l16 = lane & 15, quad = lane >> 4;
    const int bh = blockIdx.y;
    const int x = blockIdx.x;    // 0..7
    const int b = bh >> 4, h = bh & 15;
    const int qt = (b < 2) ? x : (7 - x);

    const _Float16* Qb = Qg + (size_t)bh * TSEQ * HD;
    const _Float16* Kb = Kg + (size_t)bh * TSEQ * HD;
    const _Float16* Vb = VTg + (size_t)bh * HD * TSEQ;

    const _Float16 ksc = (_Float16)(0.125f * 1.44269504089f);  // 1/sqrt(64)*log2(e)
    const floatx4 zero = {0.f, 0.f, 0.f, 0.f};

    half8 qf[2][2];
#pragma unroll
    for (int g = 0; g < 2; g++) {
        const _Float16* qrow = Qb + (size_t)(qt * 256 + g * 128 + w * 16 + l16) * HD;
        qf[g][0] = *(const half8*)(qrow + quad * 8);
        qf[g][1] = *(const half8*)(qrow + 32 + quad * 8);
#pragma unroll
        for (int e = 0; e < 8; e++) { qf[g][0][e] *= ksc; qf[g][1][e] *= ksc; }
    }

    floatx4 o[2][4];
#pragma unroll
    for (int g = 0; g < 2; g++)
#pragma unroll
        for (int dt = 0; dt < 4; dt++) o[g][dt] = zero;
    float lsum[2] = {0.f, 0.f};

    const int srow8 = lane >> 3;
    const int scol8 = ((lane & 7) ^ (lane >> 3)) * 8;   // XOR-8 swizzled col (halves)

    auto stage = [&](int bf, int kt2) {
        const int row = w * 8 + srow8;                  // 8 waves -> 1 chunk each
        async16(Kb + (size_t)(kt2 * 64 + row) * HD + scol8, &Ks[bf][w * 512]);
        async16(Vb + (size_t)row * TSEQ + kt2 * 64 + scol8, &Vt[bf][w * 512]);
    };

    const int kmax = 4 * qt + 3;
    stage(0, 0);
    int buf = 0;
    for (int kt = 0; kt <= kmax; ++kt) {
        __syncthreads();                   // buf staged (vmcnt drain), buf^1 free
        if (kt < kmax) stage(buf ^ 1, kt + 1);

        // K fragments (shared by both q-groups)
        half8 kf0[4], kf1[4];
#pragma unroll
        for (int nj = 0; nj < 4; nj++) {
            const int rb = (nj * 16 + l16) * 64;
            kf0[nj] = *(const half8*)&Ks[buf][rb + ((quad ^ (l16 & 7)) * 8)];
            kf1[nj] = *(const half8*)&Ks[buf][rb + (((quad ^ 4) ^ (l16 & 7)) * 8)];
        }

        const bool doA = (kt <= 4 * qt + 1);   // g=0 needs tiles up to 4qt+1
        half8 pf[2][2];
#pragma unroll
        for (int g = 0; g < 2; g++) {
            if (g == 0 && !doA) continue;  // wave-uniform skip (last 2 tiles g=1 only)
            floatx4 st[4];
#pragma unroll
            for (int nj = 0; nj < 4; nj++) {
                floatx4 t = mfma16x32(kf0[nj], qf[g][0], zero);
                st[nj] = mfma16x32(kf1[nj], qf[g][1], t);
            }
            if (kt * 64 + 63 > qt * 256 + g * 128 + w * 16) {   // boundary tiles only
                const int klim = qt * 256 + g * 128 + w * 16 + l16 - kt * 64;
#pragma unroll
                for (int nj = 0; nj < 4; nj++)
#pragma unroll
                    for (int r = 0; r < 4; r++) {
                        int key = nj * 16 + quad * 4 + r;
                        if (key > klim) st[nj][r] = -1e30f;   // exp2 -> 0
                    }
            }
#pragma unroll
            for (int nj = 0; nj < 4; nj++)
#pragma unroll
                for (int r = 0; r < 4; r++) {
                    float p = __builtin_amdgcn_exp2f(st[nj][r]);
                    lsum[g] += p;
                    pf[g][nj >> 1][(nj & 1) * 4 + r] = (_Float16)p;
                }
        }

        // O += P*V, paired 16x16x32; V-fragments shared across groups
#pragma unroll
        for (int u = 0; u < 2; u++) {
#pragma unroll
            for (int dt = 0; dt < 4; dt++) {
                const int rb = (dt * 16 + l16) * 64;
                const int g0 = u * 4 + (quad >> 1);
                const int sub = (quad & 1) * 4;
                half4_t lo = *(const half4_t*)&Vt[buf][rb + ((g0 ^ (l16 & 7)) * 8 + sub)];
                half4_t hi = *(const half4_t*)&Vt[buf][rb + (((g0 + 2) ^ (l16 & 7)) * 8 + sub)];
                half8 vf;
                vf[0] = lo[0]; vf[1] = lo[1]; vf[2] = lo[2]; vf[3] = lo[3];
                vf[4] = hi[0]; vf[5] = hi[1]; vf[6] = hi[2]; vf[7] = hi[3];
                if (doA) o[0][dt] = mfma16x32(pf[0][u], vf, o[0][dt]);
                o[1][dt] = mfma16x32(pf[1][u], vf, o[1][dt]);
            }
        }
        buf ^= 1;
    }

#pragma unroll
    for (int g = 0; g < 2; g++) {
        float lt = lsum[g];
        lt += __shfl_xor(lt, 16);
        lt += __shfl_xor(lt, 32);      // lt = full l for query w*16+l16 (this group)
        float linv[4];
#pragma unroll
        for (int r = 0; r < 4; r++) linv[r] = 1.0f / __shfl(lt, quad * 4 + r);
#pragma unroll
        for (int dt = 0; dt < 4; dt++)
#pragma unroll
            for (int r = 0; r < 4; r++) {
                int q = qt * 256 + g * 128 + w * 16 + quad * 4 + r;
                int d = dt * 16 + l16;
                Y[((size_t)(b * TSEQ + q)) * CEMB + h * HD + d] = (_Float16)(o[g][dt][r] * linv[r]);
            }
    }
}

extern "C" void kernel_launch(void* const* d_in, const int* in_sizes, int n_in,
                              void* d_out, int out_size, void* d_ws, size_t ws_size,
                              hipStream_t stream) {
    const float* x0     = (const float*)d_in[0];
    const float* w_attn = (const float*)d_in[1];
    const float* w_proj = (const float*)d_in[2];
    float* out = (float*)d_out;

    _Float16* xh  = (_Float16*)d_ws;                       // [8192][1024]
    _Float16* wqt = xh  + (size_t)MROWS * CEMB;            // [3072][1024] (w_attn^T)
    _Float16* wpt = wqt + (size_t)3 * CEMB * CEMB;         // [1024][1024] (w_proj^T)
    _Float16* qh  = wpt + (size_t)CEMB * CEMB;             // Q [bh][t][d]
    _Float16* kh  = qh  + (size_t)MROWS * CEMB;            // K [bh][t][d]
    _Float16* vt  = kh  + (size_t)MROWS * CEMB;            // V^T [bh][d][t]
    _Float16* yh  = vt  + (size_t)MROWS * CEMB;            // [8192][1024]

    cvt_fp32_fp16<<<(MROWS * CEMB) / (256 * 8), 256, 0, stream>>>(x0, xh);
    transpose_cvt<<<dim3(3 * CEMB / 32, CEMB / 32), dim3(32, 8), 0, stream>>>(w_attn, wqt, CEMB, 3 * CEMB);
    transpose_cvt<<<dim3(CEMB / 32, CEMB / 32), dim3(32, 8), 0, stream>>>(w_proj, wpt, CEMB, CEMB);

    gemm_nt8<0><<<dim3(MROWS / 128, 3 * CEMB / 256), 512, 0, stream>>>(xh, wqt, nullptr, qh, vt, 3 * CEMB, CEMB);
    attn_fwd<<<dim3(TSEQ / 256, NB * NH), 512, 0, stream>>>(qh, kh, vt, yh);
    gemm_nt8<1><<<dim3(MROWS / 128, CEMB / 256), 512, 0, stream>>>(yh, wpt, out, nullptr, nullptr, CEMB, CEMB);
}